// Round 1
// baseline (721.199 us; speedup 1.0000x reference)
//
#include <hip/hip_runtime.h>
#include <cstdint>
#include <cstddef>

// ---------------------------------------------------------------------------
// ReweightGNN: 3x GraphSAGE-reweight layers (lmda=1.0) + dropout(0.5) + 2-layer MLP
// N=50000 nodes, E=800000 edges, D=128 everywhere, DOUT=10.
// Outputs: h [N,128] then y [N,10], fp32, concatenated in d_out.
// ---------------------------------------------------------------------------

#define N_NODES 50000
#define N_EDGES 800000
#define DGN 128
#define DOUT 10
#define NELEM (N_NODES * DGN)       // 6,400,000
#define H_HALF (NELEM / 2)          // 3,200,000  (legacy threefry pairing)

// JAX >= 0.4.36 defaults jax_threefry_partitionable=True. If absmax fails at
// O(1) with masks as the only candidate, flip this to 0 (legacy scheme).
#define JAX_PARTITIONABLE 1

// ---------------------------------------------------------------------------
// threefry2x32 (exact JAX algorithm): 5 groups of 4 rounds, key injections.
// ---------------------------------------------------------------------------
__host__ __device__ static inline void tf2x32(unsigned k0, unsigned k1,
                                              unsigned c0, unsigned c1,
                                              unsigned& o0, unsigned& o1) {
  unsigned ks2 = k0 ^ k1 ^ 0x1BD11BDAu;
  unsigned x0 = c0 + k0;
  unsigned x1 = c1 + k1;
#define TFR(r) { x0 += x1; x1 = (x1 << (r)) | (x1 >> (32 - (r))); x1 ^= x0; }
  TFR(13) TFR(15) TFR(26) TFR(6)
  x0 += k1;  x1 += ks2 + 1u;
  TFR(17) TFR(29) TFR(16) TFR(24)
  x0 += ks2; x1 += k0 + 2u;
  TFR(13) TFR(15) TFR(26) TFR(6)
  x0 += k0;  x1 += k1 + 3u;
  TFR(17) TFR(29) TFR(16) TFR(24)
  x0 += k1;  x1 += ks2 + 4u;
  TFR(13) TFR(15) TFR(26) TFR(6)
  x0 += ks2; x1 += k0 + 5u;
#undef TFR
  o0 = x0; o1 = x1;
}

// dropout keep-mask. bernoulli(key,0.5): uniform u = bitcast((bits>>9)|0x3f800000)-1,
// keep iff u < 0.5  <=>  top bit of bits == 0 (exact).
#if JAX_PARTITIONABLE
__global__ __launch_bounds__(256) void mask_gen(unsigned char* __restrict__ m,
                                                unsigned k0, unsigned k1) {
  int i = blockIdx.x * 256 + threadIdx.x;
  if (i >= NELEM) return;
  unsigned o0, o1;
  tf2x32(k0, k1, 0u, (unsigned)i, o0, o1);
  unsigned bits = o0 ^ o1;           // partitionable 32-bit bits = o0 ^ o1
  m[i] = (unsigned char)((bits >> 31) ^ 1u);
}
#else
__global__ __launch_bounds__(256) void mask_gen(unsigned char* __restrict__ m,
                                                unsigned k0, unsigned k1) {
  int j = blockIdx.x * 256 + threadIdx.x;   // pair (j, j+H_HALF)
  if (j >= H_HALF) return;
  unsigned o0, o1;
  tf2x32(k0, k1, (unsigned)j, (unsigned)(j + H_HALF), o0, o1);
  m[j] = (unsigned char)((o0 >> 31) ^ 1u);
  m[j + H_HALF] = (unsigned char)((o1 >> 31) ^ 1u);
}
#endif

// ---------------------------------------------------------------------------
// Edge bucketing (CSR by row) so aggregation needs no float atomics.
// ---------------------------------------------------------------------------
__global__ __launch_bounds__(256) void count_kernel(const int* __restrict__ ei,
                                                    int* __restrict__ cnt) {
  int e = blockIdx.x * 256 + threadIdx.x;
  if (e >= N_EDGES) return;
  int r = ei[e];
  r = (r < 0) ? 0 : (r >= N_NODES ? N_NODES - 1 : r);   // safety clamp
  atomicAdd(&cnt[r], 1);
}

__global__ __launch_bounds__(256) void scan_local(const int* __restrict__ cnt,
                                                  int* __restrict__ rowptr,
                                                  int* __restrict__ bsum) {
  __shared__ int s[256];
  int t = threadIdx.x;
  int idx = blockIdx.x * 256 + t;
  int v = (idx < N_NODES) ? cnt[idx] : 0;
  s[t] = v;
  __syncthreads();
  for (int off = 1; off < 256; off <<= 1) {
    int tv = (t >= off) ? s[t - off] : 0;
    __syncthreads();
    s[t] += tv;
    __syncthreads();
  }
  if (idx < N_NODES) rowptr[idx] = s[t] - v;   // block-local exclusive
  if (t == 255) bsum[blockIdx.x] = s[255];
}

__global__ __launch_bounds__(256) void scan_bsum(const int* __restrict__ bsum,
                                                 int* __restrict__ boff, int nb) {
  __shared__ int s[256];
  int t = threadIdx.x;
  int v = (t < nb) ? bsum[t] : 0;
  s[t] = v;
  __syncthreads();
  for (int off = 1; off < 256; off <<= 1) {
    int tv = (t >= off) ? s[t - off] : 0;
    __syncthreads();
    s[t] += tv;
    __syncthreads();
  }
  if (t < nb) boff[t] = s[t] - v;
}

__global__ __launch_bounds__(256) void scan_final(int* __restrict__ rowptr,
                                                  const int* __restrict__ boff,
                                                  const int* __restrict__ cnt,
                                                  int* __restrict__ cursor,
                                                  float* __restrict__ invc) {
  int idx = blockIdx.x * 256 + threadIdx.x;
  if (idx >= N_NODES) return;
  int rp = rowptr[idx] + boff[blockIdx.x];
  rowptr[idx] = rp;
  cursor[idx] = rp;
  int c = cnt[idx];
  invc[idx] = 1.0f / (float)(c > 1 ? c : 1);   // 1/max(cnt,1)
}

__global__ __launch_bounds__(256) void bucket_kernel(const int* __restrict__ ei,
                                                     const float* __restrict__ ew,
                                                     int* __restrict__ cursor,
                                                     int* __restrict__ col_s,
                                                     float* __restrict__ ew_s) {
  int e = blockIdx.x * 256 + threadIdx.x;
  if (e >= N_EDGES) return;
  int r = ei[e];
  r = (r < 0) ? 0 : (r >= N_NODES ? N_NODES - 1 : r);
  int c = ei[N_EDGES + e];
  c = (c < 0) ? 0 : (c >= N_NODES ? N_NODES - 1 : c);
  int pos = atomicAdd(&cursor[r], 1);
  col_s[pos] = c;
  ew_s[pos] = ew[e];
}

// ---------------------------------------------------------------------------
// Aggregation: one 128-thread block per row.
// agg[r,:] = invc[r] * sum_e ew_e * hlin[col_e, :]   (lmda=1.0 => weight=ew)
// ---------------------------------------------------------------------------
__global__ __launch_bounds__(128) void agg_kernel(const float* __restrict__ hlin,
                                                  const int* __restrict__ rowptr,
                                                  const int* __restrict__ cnt,
                                                  const int* __restrict__ col_s,
                                                  const float* __restrict__ ew_s,
                                                  const float* __restrict__ invc,
                                                  float* __restrict__ agg) {
  const int r = blockIdx.x;
  const int t = threadIdx.x;
  const int start = rowptr[r];
  const int num = cnt[r];
  float acc = 0.0f;
  int e = 0;
  for (; e + 2 <= num; e += 2) {
    int c0 = col_s[start + e];
    int c1 = col_s[start + e + 1];
    float w0 = ew_s[start + e];
    float w1 = ew_s[start + e + 1];
    acc += w0 * hlin[(size_t)c0 * DGN + t];
    acc += w1 * hlin[(size_t)c1 * DGN + t];
  }
  if (e < num) {
    int c0 = col_s[start + e];
    acc += ew_s[start + e] * hlin[(size_t)c0 * DGN + t];
  }
  agg[(size_t)r * DGN + t] = acc * invc[r];
}

// ---------------------------------------------------------------------------
// Tiled fp32 GEMM: out[N,128] = [A0|A1][N,K] @ W[K,128] + bias, opt ReLU, opt
// dropout mask (out = mask ? 2*relu(v) : 0). NCH = K/16 (8 or 16). A0 covers
// k<128, A1 covers k>=128; both have row stride 128 (concat never materialized).
// Block: 256 thr, tile 128x128, BK=16, 8x8 microtile.
// ---------------------------------------------------------------------------
template <int NCH, bool RELU, bool MASK>
__global__ __launch_bounds__(256) void gemm128(const float* __restrict__ A0,
                                               const float* __restrict__ A1,
                                               const float* __restrict__ W,
                                               const float* __restrict__ bias,
                                               const unsigned char* __restrict__ mask,
                                               float* __restrict__ out) {
  __shared__ float As[16][132];   // [k][m], stride 132 (16B-aligned rows, pad)
  __shared__ float Bs[16][132];   // [k][n]
  const int tid = threadIdx.x;
  const int m0 = blockIdx.x * 128;
  const int ty = tid >> 4;        // 0..15 row group (8 rows)
  const int tx = tid & 15;        // 0..15 col group (8 cols)
  const int lar = tid >> 2;       // A-load: row within 64-row pass
  const int lak = (tid & 3) * 4;  // A-load: k offset (float4)
  const int lbk = tid >> 5;       // B-load: k row within 8-row pass
  const int lbc = (tid & 31) * 4; // B-load: col (float4)

  float acc[8][8] = {};

  for (int kb = 0; kb < NCH; ++kb) {
    const int kglob = kb * 16;
    const float* Ab = (kglob < 128) ? A0 : A1;
    const int koff = kglob & 127;

#pragma unroll
    for (int p = 0; p < 2; ++p) {
      int rl = lar + p * 64;
      int rg = m0 + rl;
      if (rg >= N_NODES) rg = N_NODES - 1;   // clamp; unstored rows
      const float4 v = *(const float4*)(Ab + (size_t)rg * 128 + koff + lak);
      As[lak + 0][rl] = v.x;
      As[lak + 1][rl] = v.y;
      As[lak + 2][rl] = v.z;
      As[lak + 3][rl] = v.w;
    }
#pragma unroll
    for (int p = 0; p < 2; ++p) {
      int kl = lbk + p * 8;
      const float4 v = *(const float4*)(W + (size_t)(kglob + kl) * 128 + lbc);
      *(float4*)&Bs[kl][lbc] = v;
    }
    __syncthreads();

#pragma unroll
    for (int kk = 0; kk < 16; ++kk) {
      float a[8], b[8];
      *(float4*)&a[0] = *(const float4*)&As[kk][ty * 8];
      *(float4*)&a[4] = *(const float4*)&As[kk][ty * 8 + 4];
      *(float4*)&b[0] = *(const float4*)&Bs[kk][tx * 8];
      *(float4*)&b[4] = *(const float4*)&Bs[kk][tx * 8 + 4];
#pragma unroll
      for (int r = 0; r < 8; ++r)
#pragma unroll
        for (int c = 0; c < 8; ++c) acc[r][c] += a[r] * b[c];
    }
    __syncthreads();
  }

  float bb[8];
  *(float4*)&bb[0] = *(const float4*)(bias + tx * 8);
  *(float4*)&bb[4] = *(const float4*)(bias + tx * 8 + 4);

#pragma unroll
  for (int r = 0; r < 8; ++r) {
    int rg = m0 + ty * 8 + r;
    if (rg >= N_NODES) break;   // per-thread rows are consecutive
    float v[8];
#pragma unroll
    for (int c = 0; c < 8; ++c) {
      float t = acc[r][c] + bb[c];
      if (RELU) t = fmaxf(t, 0.0f);
      v[c] = t;
    }
    if (MASK) {
      const unsigned char* mp = mask + (size_t)rg * DGN + tx * 8;
#pragma unroll
      for (int c = 0; c < 8; ++c) v[c] = mp[c] ? 2.0f * v[c] : 0.0f;
    }
    float* op = out + (size_t)rg * DGN + tx * 8;
    *(float4*)op = *(float4*)&v[0];
    *(float4*)(op + 4) = *(float4*)&v[4];
  }
}

// ---------------------------------------------------------------------------
// MLP head 2: y[N,10] = t[N,128] @ W2[128,10] + b2. Row per thread, W2 in LDS
// (all lanes read same LDS address per step -> broadcast, conflict-free).
// ---------------------------------------------------------------------------
__global__ __launch_bounds__(256) void mlp2_kernel(const float* __restrict__ t,
                                                   const float* __restrict__ W2,
                                                   const float* __restrict__ b2,
                                                   float* __restrict__ y) {
  __shared__ float Ws[128 * DOUT];
  __shared__ float bs[DOUT];
  for (int i = threadIdx.x; i < 128 * DOUT; i += 256) Ws[i] = W2[i];
  if (threadIdx.x < DOUT) bs[threadIdx.x] = b2[threadIdx.x];
  __syncthreads();
  int row = blockIdx.x * 256 + threadIdx.x;
  if (row >= N_NODES) return;
  float acc[DOUT];
#pragma unroll
  for (int c = 0; c < DOUT; ++c) acc[c] = bs[c];
  const float4* tp = (const float4*)(t + (size_t)row * 128);
#pragma unroll 8
  for (int k4 = 0; k4 < 32; ++k4) {
    float4 v = tp[k4];
    const float* wr = &Ws[k4 * 4 * DOUT];
#pragma unroll
    for (int c = 0; c < DOUT; ++c)
      acc[c] += v.x * wr[c] + v.y * wr[DOUT + c] + v.z * wr[2 * DOUT + c] +
                v.w * wr[3 * DOUT + c];
  }
  float* yp = y + (size_t)row * DOUT;
#pragma unroll
  for (int c = 0; c < DOUT; ++c) yp[c] = acc[c];
}

// ---------------------------------------------------------------------------
extern "C" void kernel_launch(void* const* d_in, const int* in_sizes, int n_in,
                              void* d_out, int out_size, void* d_ws, size_t ws_size,
                              hipStream_t stream) {
  const float* x        = (const float*)d_in[0];
  const int*   ei       = (const int*)d_in[1];    // [2,E]: row then col
  const float* ew       = (const float*)d_in[2];
  const float* W_lin_in = (const float*)d_in[3];
  const float* b_lin_in = (const float*)d_in[4];
  const float* W_agg_in = (const float*)d_in[5];
  const float* b_agg_in = (const float*)d_in[6];
  const float* W_lin_h  = (const float*)d_in[7];
  const float* b_lin_h  = (const float*)d_in[8];
  const float* W_agg_h  = (const float*)d_in[9];
  const float* b_agg_h  = (const float*)d_in[10];
  const float* W_mlp1   = (const float*)d_in[11];
  const float* b_mlp1   = (const float*)d_in[12];
  const float* W_mlp2   = (const float*)d_in[13];
  const float* b_mlp2   = (const float*)d_in[14];

  float* hout = (float*)d_out;                    // [N,128]
  float* yout = hout + (size_t)NELEM;             // [N,10]

  // workspace carve (256B-aligned)
  char* p = (char*)d_ws;
  auto alloc = [&](size_t bytes) {
    char* q = p;
    p += (bytes + 255) & ~(size_t)255;
    return q;
  };
  int*   cnt    = (int*)alloc((size_t)N_NODES * 4);
  int*   rowptr = (int*)alloc((size_t)N_NODES * 4);
  int*   cursor = (int*)alloc((size_t)N_NODES * 4);
  float* invc   = (float*)alloc((size_t)N_NODES * 4);
  int*   bsum   = (int*)alloc(256 * 4);
  int*   boff   = (int*)alloc(256 * 4);
  int*   col_s  = (int*)alloc((size_t)N_EDGES * 4);
  float* ew_s   = (float*)alloc((size_t)N_EDGES * 4);
  float* f0     = (float*)alloc((size_t)NELEM * 4);
  float* f1     = (float*)alloc((size_t)NELEM * 4);
  float* f2     = (float*)alloc((size_t)NELEM * 4);
  unsigned char* maskb = (unsigned char*)alloc((size_t)NELEM);

  // dropout keys: dk = jax.random.split(jax.random.key(42), 3); key data = (0,42)
  unsigned dk[3][2];
#if JAX_PARTITIONABLE
  for (unsigned i = 0; i < 3; ++i) tf2x32(0u, 42u, 0u, i, dk[i][0], dk[i][1]);
#else
  {
    unsigned a0, b0, a1, b1, a2, b2v;
    tf2x32(0u, 42u, 0u, 3u, a0, b0);
    tf2x32(0u, 42u, 1u, 4u, a1, b1);
    tf2x32(0u, 42u, 2u, 5u, a2, b2v);
    dk[0][0] = a0; dk[0][1] = a1;
    dk[1][0] = a2; dk[1][1] = b0;
    dk[2][0] = b1; dk[2][1] = b2v;
  }
#endif

  const int EB = (N_EDGES + 255) / 256;           // 3125
  const int NB = (N_NODES + 255) / 256;           // 196
  const int GB = (N_NODES + 127) / 128;           // 391
#if JAX_PARTITIONABLE
  const int MB = (NELEM + 255) / 256;             // 25000
#else
  const int MB = (H_HALF + 255) / 256;            // 12500
#endif

  // ---- CSR build ----
  hipMemsetAsync(cnt, 0, (size_t)N_NODES * 4, stream);
  count_kernel<<<EB, 256, 0, stream>>>(ei, cnt);
  scan_local<<<NB, 256, 0, stream>>>(cnt, rowptr, bsum);
  scan_bsum<<<1, 256, 0, stream>>>(bsum, boff, NB);
  scan_final<<<NB, 256, 0, stream>>>(rowptr, boff, cnt, cursor, invc);
  bucket_kernel<<<EB, 256, 0, stream>>>(ei, ew, cursor, col_s, ew_s);

  // ---- layer 1 ----
  gemm128<8, false, false><<<GB, 256, 0, stream>>>(x, x, W_lin_in, b_lin_in, maskb, f0);
  agg_kernel<<<N_NODES, 128, 0, stream>>>(f0, rowptr, cnt, col_s, ew_s, invc, f1);
  mask_gen<<<MB, 256, 0, stream>>>(maskb, dk[0][0], dk[0][1]);
  gemm128<16, true, true><<<GB, 256, 0, stream>>>(f1, x, W_agg_in, b_agg_in, maskb, f2);

  // ---- layer 2 ----
  gemm128<8, false, false><<<GB, 256, 0, stream>>>(f2, f2, W_lin_h, b_lin_h, maskb, f0);
  agg_kernel<<<N_NODES, 128, 0, stream>>>(f0, rowptr, cnt, col_s, ew_s, invc, f1);
  mask_gen<<<MB, 256, 0, stream>>>(maskb, dk[1][0], dk[1][1]);
  gemm128<16, true, true><<<GB, 256, 0, stream>>>(f1, f2, W_agg_h, b_agg_h, maskb, f0);

  // ---- layer 3 (epilogue writes h straight to d_out) ----
  gemm128<8, false, false><<<GB, 256, 0, stream>>>(f0, f0, W_lin_h, b_lin_h, maskb, f2);
  agg_kernel<<<N_NODES, 128, 0, stream>>>(f2, rowptr, cnt, col_s, ew_s, invc, f1);
  mask_gen<<<MB, 256, 0, stream>>>(maskb, dk[2][0], dk[2][1]);
  gemm128<16, true, true><<<GB, 256, 0, stream>>>(f1, f0, W_agg_h, b_agg_h, maskb, hout);

  // ---- MLP head ----
  gemm128<8, true, false><<<GB, 256, 0, stream>>>(hout, hout, W_mlp1, b_mlp1, maskb, f0);
  mlp2_kernel<<<NB, 256, 0, stream>>>(f0, W_mlp2, b_mlp2, yout);
}

// Round 2
// 577.071 us; speedup vs baseline: 1.2498x; 1.2498x over previous
//
#include <hip/hip_runtime.h>
#include <cstdint>
#include <cstddef>

// ---------------------------------------------------------------------------
// ReweightGNN: 3x GraphSAGE-reweight layers (lmda=1.0) + dropout(0.5) + 2-layer MLP
// N=50000, E=800000, D=128, DOUT=10. Outputs: h [N,128] fp32, y [N,10] fp32.
// R2: all big GEMMs moved to bf16 MFMA 16x16x32; activations staged in bf16.
// ---------------------------------------------------------------------------

#define N_NODES 50000
#define N_EDGES 800000
#define DGN 128
#define DOUT 10
#define NELEM (N_NODES * DGN)       // 6,400,000

typedef __attribute__((ext_vector_type(8))) short bf16x8;   // 8 bf16 = 4 VGPRs
typedef __attribute__((ext_vector_type(4))) float f32x4;

__host__ __device__ static inline unsigned short f2bf(float f) {
  union { float f; unsigned u; } c; c.f = f;
  unsigned u = c.u;
  return (unsigned short)((u + 0x7fffu + ((u >> 16) & 1u)) >> 16);  // RNE
}
__device__ static inline float bf2f(unsigned short h) {
  return __uint_as_float(((unsigned)h) << 16);
}

// ---------------------------------------------------------------------------
// threefry2x32 (exact JAX): 5 groups of 4 rounds, key injections.
// ---------------------------------------------------------------------------
__host__ __device__ static inline void tf2x32(unsigned k0, unsigned k1,
                                              unsigned c0, unsigned c1,
                                              unsigned& o0, unsigned& o1) {
  unsigned ks2 = k0 ^ k1 ^ 0x1BD11BDAu;
  unsigned x0 = c0 + k0;
  unsigned x1 = c1 + k1;
#define TFR(r) { x0 += x1; x1 = (x1 << (r)) | (x1 >> (32 - (r))); x1 ^= x0; }
  TFR(13) TFR(15) TFR(26) TFR(6)
  x0 += k1;  x1 += ks2 + 1u;
  TFR(17) TFR(29) TFR(16) TFR(24)
  x0 += ks2; x1 += k0 + 2u;
  TFR(13) TFR(15) TFR(26) TFR(6)
  x0 += k0;  x1 += k1 + 3u;
  TFR(17) TFR(29) TFR(16) TFR(24)
  x0 += k1;  x1 += ks2 + 4u;
  TFR(13) TFR(15) TFR(26) TFR(6)
  x0 += ks2; x1 += k0 + 5u;
#undef TFR
  o0 = x0; o1 = x1;
}

// partitionable threefry: bits(i) = o0^o1 of tf(key, 0, i); keep iff bit31==0
__global__ __launch_bounds__(256) void mask_gen(unsigned char* __restrict__ m,
                                                unsigned k0, unsigned k1) {
  int i = blockIdx.x * 256 + threadIdx.x;
  if (i >= NELEM) return;
  unsigned o0, o1;
  tf2x32(k0, k1, 0u, (unsigned)i, o0, o1);
  unsigned bits = o0 ^ o1;
  m[i] = (unsigned char)((bits >> 31) ^ 1u);
}

// ---------------------------------------------------------------------------
// CSR build (unchanged from R1 — verified correct)
// ---------------------------------------------------------------------------
__global__ __launch_bounds__(256) void count_kernel(const int* __restrict__ ei,
                                                    int* __restrict__ cnt) {
  int e = blockIdx.x * 256 + threadIdx.x;
  if (e >= N_EDGES) return;
  int r = ei[e];
  r = (r < 0) ? 0 : (r >= N_NODES ? N_NODES - 1 : r);
  atomicAdd(&cnt[r], 1);
}

__global__ __launch_bounds__(256) void scan_local(const int* __restrict__ cnt,
                                                  int* __restrict__ rowptr,
                                                  int* __restrict__ bsum) {
  __shared__ int s[256];
  int t = threadIdx.x;
  int idx = blockIdx.x * 256 + t;
  int v = (idx < N_NODES) ? cnt[idx] : 0;
  s[t] = v;
  __syncthreads();
  for (int off = 1; off < 256; off <<= 1) {
    int tv = (t >= off) ? s[t - off] : 0;
    __syncthreads();
    s[t] += tv;
    __syncthreads();
  }
  if (idx < N_NODES) rowptr[idx] = s[t] - v;
  if (t == 255) bsum[blockIdx.x] = s[255];
}

__global__ __launch_bounds__(256) void scan_bsum(const int* __restrict__ bsum,
                                                 int* __restrict__ boff, int nb) {
  __shared__ int s[256];
  int t = threadIdx.x;
  int v = (t < nb) ? bsum[t] : 0;
  s[t] = v;
  __syncthreads();
  for (int off = 1; off < 256; off <<= 1) {
    int tv = (t >= off) ? s[t - off] : 0;
    __syncthreads();
    s[t] += tv;
    __syncthreads();
  }
  if (t < nb) boff[t] = s[t] - v;
}

__global__ __launch_bounds__(256) void scan_final(int* __restrict__ rowptr,
                                                  const int* __restrict__ boff,
                                                  const int* __restrict__ cnt,
                                                  int* __restrict__ cursor,
                                                  float* __restrict__ invc) {
  int idx = blockIdx.x * 256 + threadIdx.x;
  if (idx >= N_NODES) return;
  int rp = rowptr[idx] + boff[blockIdx.x];
  rowptr[idx] = rp;
  cursor[idx] = rp;
  int c = cnt[idx];
  invc[idx] = 1.0f / (float)(c > 1 ? c : 1);
}

__global__ __launch_bounds__(256) void bucket_kernel(const int* __restrict__ ei,
                                                     const float* __restrict__ ew,
                                                     int* __restrict__ cursor,
                                                     int* __restrict__ col_s,
                                                     float* __restrict__ ew_s) {
  int e = blockIdx.x * 256 + threadIdx.x;
  if (e >= N_EDGES) return;
  int r = ei[e];
  r = (r < 0) ? 0 : (r >= N_NODES ? N_NODES - 1 : r);
  int c = ei[N_EDGES + e];
  c = (c < 0) ? 0 : (c >= N_NODES ? N_NODES - 1 : c);
  int pos = atomicAdd(&cursor[r], 1);
  col_s[pos] = c;
  ew_s[pos] = ew[e];
}

// ---------------------------------------------------------------------------
// Aggregation: one 128-thread block per row; bf16 in, fp32 accumulate, bf16 out.
// agg[r,:] = invc[r] * sum_e ew_e * hlin[col_e, :]
// ---------------------------------------------------------------------------
__global__ __launch_bounds__(128) void agg_kernel(const unsigned short* __restrict__ hlin,
                                                  const int* __restrict__ rowptr,
                                                  const int* __restrict__ cnt,
                                                  const int* __restrict__ col_s,
                                                  const float* __restrict__ ew_s,
                                                  const float* __restrict__ invc,
                                                  unsigned short* __restrict__ agg) {
  const int r = blockIdx.x;
  const int t = threadIdx.x;
  const int start = rowptr[r];
  const int num = cnt[r];
  float acc = 0.0f;
  int e = 0;
  for (; e + 2 <= num; e += 2) {
    int c0 = col_s[start + e];
    int c1 = col_s[start + e + 1];
    float w0 = ew_s[start + e];
    float w1 = ew_s[start + e + 1];
    acc += w0 * bf2f(hlin[(size_t)c0 * DGN + t]);
    acc += w1 * bf2f(hlin[(size_t)c1 * DGN + t]);
  }
  if (e < num)
    acc += ew_s[start + e] * bf2f(hlin[(size_t)col_s[start + e] * DGN + t]);
  agg[(size_t)r * DGN + t] = f2bf(acc * invc[r]);
}

// ---------------------------------------------------------------------------
// bf16 MFMA GEMM: out[N,128] = [A0|A1][N,KTOT] @ W[KTOT,128] + bias.
// A0 covers k<128, A1 covers k>=128 (row stride 128 each, concat virtual).
// Wt is bf16 W^T: Wt[n*KTOT + k] = W[k,n]  (B-operand wants contiguous k).
// Block 256 thr = 4 waves (2x2), tile 128x128, wave = 64x64 = 4x4 MFMA tiles.
// BK=64 LDS staging, rows padded to 72 (bank stride 4 -> 2-way max, free).
// Epilogue: +bias, opt ReLU, opt dropout (mask?2v:0), opt fp32 and bf16 stores.
// ---------------------------------------------------------------------------
template <int KTOT, bool RELU, bool MASK, bool WF32, bool WBF>
__global__ __launch_bounds__(256) void mfma_gemm(
    const unsigned short* __restrict__ A0, const unsigned short* __restrict__ A1,
    const unsigned short* __restrict__ Wt, const float* __restrict__ bias,
    const unsigned char* __restrict__ mask,
    float* __restrict__ outf, unsigned short* __restrict__ outb) {
  constexpr int BK = 64;
  constexpr int LDK = BK + 8;   // 72 elem rows; 144 B (16B-aligned), bank-safe
  __shared__ unsigned short Als[128 * LDK];
  __shared__ unsigned short Bls[128 * LDK];
  const int tid = threadIdx.x;
  const int m0 = blockIdx.x * 128;
  const int lane = tid & 63;
  const int wid = tid >> 6;
  const int wm = (wid >> 1) * 64;
  const int wn = (wid & 1) * 64;
  const int lrow = tid >> 1;          // staging row 0..127
  const int lkh = (tid & 1) * 32;     // staging k-offset 0/32

  int arow = m0 + lrow;
  if (arow >= N_NODES) arow = N_NODES - 1;   // clamp; stores guarded below

  f32x4 acc[4][4];
#pragma unroll
  for (int i = 0; i < 4; ++i)
#pragma unroll
    for (int j = 0; j < 4; ++j)
#pragma unroll
      for (int r = 0; r < 4; ++r) acc[i][j][r] = 0.0f;

  for (int kb = 0; kb < KTOT; kb += BK) {
    const unsigned short* Asrc = (kb < 128) ? A0 : A1;
    const unsigned short* ap = Asrc + (size_t)arow * 128 + (kb & 127) + lkh;
    const unsigned short* bp = Wt + (size_t)lrow * KTOT + kb + lkh;
    unsigned short* al = &Als[lrow * LDK + lkh];
    unsigned short* bl = &Bls[lrow * LDK + lkh];
#pragma unroll
    for (int j = 0; j < 4; ++j) {
      *(uint4*)(al + j * 8) = *(const uint4*)(ap + j * 8);
      *(uint4*)(bl + j * 8) = *(const uint4*)(bp + j * 8);
    }
    __syncthreads();
#pragma unroll
    for (int ks = 0; ks < BK; ks += 32) {
      bf16x8 af[4], bfr[4];
#pragma unroll
      for (int t = 0; t < 4; ++t) {
        af[t]  = *(const bf16x8*)&Als[(wm + t * 16 + (lane & 15)) * LDK + ks + (lane >> 4) * 8];
        bfr[t] = *(const bf16x8*)&Bls[(wn + t * 16 + (lane & 15)) * LDK + ks + (lane >> 4) * 8];
      }
#pragma unroll
      for (int i = 0; i < 4; ++i)
#pragma unroll
        for (int j = 0; j < 4; ++j)
          acc[i][j] = __builtin_amdgcn_mfma_f32_16x16x32_bf16(af[i], bfr[j], acc[i][j], 0, 0, 0);
    }
    __syncthreads();
  }

  // epilogue: C/D map col=lane&15, row=(lane>>4)*4+reg  [verified m89/m91]
  const int lm = lane >> 4;
  const int ln = lane & 15;
#pragma unroll
  for (int j = 0; j < 4; ++j) {
    const int col = wn + j * 16 + ln;
    const float bcol = bias[col];
#pragma unroll
    for (int i = 0; i < 4; ++i) {
      const int rbase = m0 + wm + i * 16 + lm * 4;
#pragma unroll
      for (int r = 0; r < 4; ++r) {
        const int row = rbase + r;
        if (row >= N_NODES) continue;
        float v = acc[i][j][r] + bcol;
        if (RELU) v = fmaxf(v, 0.0f);
        if (MASK) v = mask[(size_t)row * DGN + col] ? 2.0f * v : 0.0f;
        if (WF32) outf[(size_t)row * DGN + col] = v;
        if (WBF)  outb[(size_t)row * DGN + col] = f2bf(v);
      }
    }
  }
}

// ---------------------------------------------------------------------------
// MLP head 2: y[N,10] = t[N,128](bf16) @ W2[128,10] + b2. Row/thread, W2 in LDS.
// ---------------------------------------------------------------------------
__global__ __launch_bounds__(256) void mlp2_kernel(const unsigned short* __restrict__ t,
                                                   const float* __restrict__ W2,
                                                   const float* __restrict__ b2,
                                                   float* __restrict__ y) {
  __shared__ float Ws[128 * DOUT];
  __shared__ float bs[DOUT];
  for (int i = threadIdx.x; i < 128 * DOUT; i += 256) Ws[i] = W2[i];
  if (threadIdx.x < DOUT) bs[threadIdx.x] = b2[threadIdx.x];
  __syncthreads();
  int row = blockIdx.x * 256 + threadIdx.x;
  if (row >= N_NODES) return;
  float acc[DOUT];
#pragma unroll
  for (int c = 0; c < DOUT; ++c) acc[c] = bs[c];
  const uint4* tp = (const uint4*)(t + (size_t)row * 128);
#pragma unroll 4
  for (int k8 = 0; k8 < 16; ++k8) {
    uint4 raw = tp[k8];
    unsigned w[4] = {raw.x, raw.y, raw.z, raw.w};
#pragma unroll
    for (int p = 0; p < 4; ++p) {
      float lo = __uint_as_float(w[p] << 16);
      float hi = __uint_as_float(w[p] & 0xffff0000u);
      const float* wr = &Ws[(k8 * 8 + p * 2) * DOUT];
#pragma unroll
      for (int c = 0; c < DOUT; ++c)
        acc[c] += lo * wr[c] + hi * wr[DOUT + c];
    }
  }
  float* yp = y + (size_t)row * DOUT;
#pragma unroll
  for (int c = 0; c < DOUT; ++c) yp[c] = acc[c];
}

// ---------------------------------------------------------------------------
// One-shot prep: x fp32 -> bf16 (vectorized)
// ---------------------------------------------------------------------------
__global__ __launch_bounds__(256) void convert_x(const float* __restrict__ x,
                                                 unsigned short* __restrict__ xb) {
  int i = blockIdx.x * 256 + threadIdx.x;
  if (i >= NELEM / 4) return;
  float4 v = ((const float4*)x)[i];
  ushort4 o;
  o.x = f2bf(v.x); o.y = f2bf(v.y); o.z = f2bf(v.z); o.w = f2bf(v.w);
  ((ushort4*)xb)[i] = o;
}

// 5 weight transposes fused: Wt[n*K+k] = bf16(W[k*128+n])
__global__ __launch_bounds__(256) void prep_weights(
    const float* __restrict__ W0, const float* __restrict__ W1,
    const float* __restrict__ W2, const float* __restrict__ W3,
    const float* __restrict__ W4,
    unsigned short* __restrict__ T0, unsigned short* __restrict__ T1,
    unsigned short* __restrict__ T2, unsigned short* __restrict__ T3,
    unsigned short* __restrict__ T4) {
  int j = blockIdx.x * 256 + threadIdx.x;
  const float* src; unsigned short* dst; int K;
  if (j < 16384)                  { src = W0; dst = T0; K = 128; }
  else if ((j -= 16384) < 32768)  { src = W1; dst = T1; K = 256; }
  else if ((j -= 32768) < 16384)  { src = W2; dst = T2; K = 128; }
  else if ((j -= 16384) < 32768)  { src = W3; dst = T3; K = 256; }
  else if ((j -= 32768) < 16384)  { src = W4; dst = T4; K = 128; }
  else return;
  int n = j / K, k = j - n * K;
  dst[j] = f2bf(src[(size_t)k * 128 + n]);
}

// ---------------------------------------------------------------------------
extern "C" void kernel_launch(void* const* d_in, const int* in_sizes, int n_in,
                              void* d_out, int out_size, void* d_ws, size_t ws_size,
                              hipStream_t stream) {
  const float* x        = (const float*)d_in[0];
  const int*   ei       = (const int*)d_in[1];
  const float* ew       = (const float*)d_in[2];
  const float* W_lin_in = (const float*)d_in[3];
  const float* b_lin_in = (const float*)d_in[4];
  const float* W_agg_in = (const float*)d_in[5];
  const float* b_agg_in = (const float*)d_in[6];
  const float* W_lin_h  = (const float*)d_in[7];
  const float* b_lin_h  = (const float*)d_in[8];
  const float* W_agg_h  = (const float*)d_in[9];
  const float* b_agg_h  = (const float*)d_in[10];
  const float* W_mlp1   = (const float*)d_in[11];
  const float* b_mlp1   = (const float*)d_in[12];
  const float* W_mlp2   = (const float*)d_in[13];
  const float* b_mlp2   = (const float*)d_in[14];

  float* hout = (float*)d_out;
  float* yout = hout + (size_t)NELEM;

  char* p = (char*)d_ws;
  auto alloc = [&](size_t bytes) {
    char* q = p;
    p += (bytes + 255) & ~(size_t)255;
    return q;
  };
  int*   cnt    = (int*)alloc((size_t)N_NODES * 4);
  int*   rowptr = (int*)alloc((size_t)N_NODES * 4);
  int*   cursor = (int*)alloc((size_t)N_NODES * 4);
  float* invc   = (float*)alloc((size_t)N_NODES * 4);
  int*   bsum   = (int*)alloc(256 * 4);
  int*   boff   = (int*)alloc(256 * 4);
  int*   col_s  = (int*)alloc((size_t)N_EDGES * 4);
  float* ew_s   = (float*)alloc((size_t)N_EDGES * 4);
  unsigned short* xb   = (unsigned short*)alloc((size_t)NELEM * 2);
  unsigned short* f0b  = (unsigned short*)alloc((size_t)NELEM * 2);
  unsigned short* aggb = (unsigned short*)alloc((size_t)NELEM * 2);
  unsigned short* hA   = (unsigned short*)alloc((size_t)NELEM * 2);
  unsigned short* hB   = (unsigned short*)alloc((size_t)NELEM * 2);
  unsigned char*  maskb = (unsigned char*)alloc((size_t)NELEM);
  unsigned short* Tli = (unsigned short*)alloc(16384 * 2);
  unsigned short* Tai = (unsigned short*)alloc(32768 * 2);
  unsigned short* Tlh = (unsigned short*)alloc(16384 * 2);
  unsigned short* Tah = (unsigned short*)alloc(32768 * 2);
  unsigned short* Tm1 = (unsigned short*)alloc(16384 * 2);

  // dropout keys: jax.random.split(jax.random.key(42), 3), partitionable
  unsigned dk[3][2];
  for (unsigned i = 0; i < 3; ++i) tf2x32(0u, 42u, 0u, i, dk[i][0], dk[i][1]);

  const int EB = (N_EDGES + 255) / 256;
  const int NB = (N_NODES + 255) / 256;
  const int GB = (N_NODES + 127) / 128;   // 391 gemm blocks
  const int MB = (NELEM + 255) / 256;

  // ---- CSR build ----
  hipMemsetAsync(cnt, 0, (size_t)N_NODES * 4, stream);
  count_kernel<<<EB, 256, 0, stream>>>(ei, cnt);
  scan_local<<<NB, 256, 0, stream>>>(cnt, rowptr, bsum);
  scan_bsum<<<1, 256, 0, stream>>>(bsum, boff, NB);
  scan_final<<<NB, 256, 0, stream>>>(rowptr, boff, cnt, cursor, invc);
  bucket_kernel<<<EB, 256, 0, stream>>>(ei, ew, cursor, col_s, ew_s);

  // ---- one-shot conversions ----
  convert_x<<<(NELEM / 4 + 255) / 256, 256, 0, stream>>>(x, xb);
  prep_weights<<<(114688 + 255) / 256, 256, 0, stream>>>(
      W_lin_in, W_agg_in, W_lin_h, W_agg_h, W_mlp1, Tli, Tai, Tlh, Tah, Tm1);

  // ---- layer 1 ----
  mfma_gemm<128, false, false, false, true><<<GB, 256, 0, stream>>>(
      xb, xb, Tli, b_lin_in, maskb, nullptr, f0b);
  agg_kernel<<<N_NODES, 128, 0, stream>>>(f0b, rowptr, cnt, col_s, ew_s, invc, aggb);
  mask_gen<<<MB, 256, 0, stream>>>(maskb, dk[0][0], dk[0][1]);
  mfma_gemm<256, true, true, false, true><<<GB, 256, 0, stream>>>(
      aggb, xb, Tai, b_agg_in, maskb, nullptr, hA);

  // ---- layer 2 ----
  mfma_gemm<128, false, false, false, true><<<GB, 256, 0, stream>>>(
      hA, hA, Tlh, b_lin_h, maskb, nullptr, f0b);
  agg_kernel<<<N_NODES, 128, 0, stream>>>(f0b, rowptr, cnt, col_s, ew_s, invc, aggb);
  mask_gen<<<MB, 256, 0, stream>>>(maskb, dk[1][0], dk[1][1]);
  mfma_gemm<256, true, true, false, true><<<GB, 256, 0, stream>>>(
      aggb, hA, Tah, b_agg_h, maskb, nullptr, hB);

  // ---- layer 3 (fp32 h straight to d_out + bf16 for mlp1) ----
  mfma_gemm<128, false, false, false, true><<<GB, 256, 0, stream>>>(
      hB, hB, Tlh, b_lin_h, maskb, nullptr, f0b);
  agg_kernel<<<N_NODES, 128, 0, stream>>>(f0b, rowptr, cnt, col_s, ew_s, invc, aggb);
  mask_gen<<<MB, 256, 0, stream>>>(maskb, dk[2][0], dk[2][1]);
  mfma_gemm<256, true, true, true, true><<<GB, 256, 0, stream>>>(
      aggb, hB, Tah, b_agg_h, maskb, hout, hA);

  // ---- MLP head ----
  mfma_gemm<128, true, false, false, true><<<GB, 256, 0, stream>>>(
      hA, hA, Tm1, b_mlp1, maskb, nullptr, aggb);
  mlp2_kernel<<<NB, 256, 0, stream>>>(aggb, W_mlp2, b_mlp2, yout);
}

// Round 3
// 467.413 us; speedup vs baseline: 1.5430x; 1.2346x over previous
//
#include <hip/hip_runtime.h>
#include <cstdint>
#include <cstddef>

// ---------------------------------------------------------------------------
// ReweightGNN: 3x GraphSAGE-reweight (lmda=1.0) + dropout(0.5) + 2-layer MLP
// N=50000, E=800000, D=128, DOUT=10. Outputs: h [N,128] fp32, y [N,10] fp32.
// R3: latency-optimized gather (wave/row, uint2, unroll4, shfl reduce),
//     64x64 GEMM tiles for occupancy, bit-packed fused dropout masks.
// ---------------------------------------------------------------------------

#define N_NODES 50000
#define N_EDGES 800000
#define DGN 128
#define DOUT 10
#define NELEM (N_NODES * DGN)       // 6,400,000
#define NMASKW (NELEM / 64)         // 100,000 uint64 words per mask

typedef __attribute__((ext_vector_type(8))) short bf16x8;
typedef __attribute__((ext_vector_type(4))) float f32x4;

__host__ __device__ static inline unsigned short f2bf(float f) {
  union { float f; unsigned u; } c; c.f = f;
  unsigned u = c.u;
  return (unsigned short)((u + 0x7fffu + ((u >> 16) & 1u)) >> 16);  // RNE
}
__device__ static inline float bflo(unsigned u) { return __uint_as_float(u << 16); }
__device__ static inline float bfhi(unsigned u) { return __uint_as_float(u & 0xffff0000u); }

// ---------------------------------------------------------------------------
// threefry2x32 (exact JAX)
// ---------------------------------------------------------------------------
__host__ __device__ static inline void tf2x32(unsigned k0, unsigned k1,
                                              unsigned c0, unsigned c1,
                                              unsigned& o0, unsigned& o1) {
  unsigned ks2 = k0 ^ k1 ^ 0x1BD11BDAu;
  unsigned x0 = c0 + k0;
  unsigned x1 = c1 + k1;
#define TFR(r) { x0 += x1; x1 = (x1 << (r)) | (x1 >> (32 - (r))); x1 ^= x0; }
  TFR(13) TFR(15) TFR(26) TFR(6)
  x0 += k1;  x1 += ks2 + 1u;
  TFR(17) TFR(29) TFR(16) TFR(24)
  x0 += ks2; x1 += k0 + 2u;
  TFR(13) TFR(15) TFR(26) TFR(6)
  x0 += k0;  x1 += k1 + 3u;
  TFR(17) TFR(29) TFR(16) TFR(24)
  x0 += k1;  x1 += ks2 + 4u;
  TFR(13) TFR(15) TFR(26) TFR(6)
  x0 += ks2; x1 += k0 + 5u;
#undef TFR
  o0 = x0; o1 = x1;
}

// All 3 dropout masks in one pass, bit-packed: word w bit l = keep(elem 64w+l).
// keep iff bit31 of (o0^o1) == 0 (exact for bernoulli(0.5)).
__global__ __launch_bounds__(256) void mask_gen3(
    unsigned long long* __restrict__ m0, unsigned long long* __restrict__ m1,
    unsigned long long* __restrict__ m2,
    unsigned k00, unsigned k01, unsigned k10, unsigned k11,
    unsigned k20, unsigned k21) {
  int i = blockIdx.x * 256 + threadIdx.x;
  if (i >= NELEM) return;
  unsigned o0, o1;
  tf2x32(k00, k01, 0u, (unsigned)i, o0, o1);
  unsigned long long b0 = __ballot(((o0 ^ o1) >> 31) == 0u);
  tf2x32(k10, k11, 0u, (unsigned)i, o0, o1);
  unsigned long long b1 = __ballot(((o0 ^ o1) >> 31) == 0u);
  tf2x32(k20, k21, 0u, (unsigned)i, o0, o1);
  unsigned long long b2 = __ballot(((o0 ^ o1) >> 31) == 0u);
  if ((threadIdx.x & 63) == 0) {
    int w = i >> 6;
    m0[w] = b0; m1[w] = b1; m2[w] = b2;
  }
}

// ---------------------------------------------------------------------------
// CSR build (verified R1/R2)
// ---------------------------------------------------------------------------
__global__ __launch_bounds__(256) void count_kernel(const int* __restrict__ ei,
                                                    int* __restrict__ cnt) {
  int e = blockIdx.x * 256 + threadIdx.x;
  if (e >= N_EDGES) return;
  int r = ei[e];
  r = (r < 0) ? 0 : (r >= N_NODES ? N_NODES - 1 : r);
  atomicAdd(&cnt[r], 1);
}

__global__ __launch_bounds__(256) void scan_local(const int* __restrict__ cnt,
                                                  int* __restrict__ rowptr,
                                                  int* __restrict__ bsum) {
  __shared__ int s[256];
  int t = threadIdx.x;
  int idx = blockIdx.x * 256 + t;
  int v = (idx < N_NODES) ? cnt[idx] : 0;
  s[t] = v;
  __syncthreads();
  for (int off = 1; off < 256; off <<= 1) {
    int tv = (t >= off) ? s[t - off] : 0;
    __syncthreads();
    s[t] += tv;
    __syncthreads();
  }
  if (idx < N_NODES) rowptr[idx] = s[t] - v;
  if (t == 255) bsum[blockIdx.x] = s[255];
}

__global__ __launch_bounds__(256) void scan_bsum(const int* __restrict__ bsum,
                                                 int* __restrict__ boff, int nb) {
  __shared__ int s[256];
  int t = threadIdx.x;
  int v = (t < nb) ? bsum[t] : 0;
  s[t] = v;
  __syncthreads();
  for (int off = 1; off < 256; off <<= 1) {
    int tv = (t >= off) ? s[t - off] : 0;
    __syncthreads();
    s[t] += tv;
    __syncthreads();
  }
  if (t < nb) boff[t] = s[t] - v;
}

__global__ __launch_bounds__(256) void scan_final(int* __restrict__ rowptr,
                                                  const int* __restrict__ boff,
                                                  const int* __restrict__ cnt,
                                                  int* __restrict__ cursor,
                                                  float* __restrict__ invc) {
  int idx = blockIdx.x * 256 + threadIdx.x;
  if (idx >= N_NODES) return;
  int rp = rowptr[idx] + boff[blockIdx.x];
  rowptr[idx] = rp;
  cursor[idx] = rp;
  int c = cnt[idx];
  invc[idx] = 1.0f / (float)(c > 1 ? c : 1);
}

__global__ __launch_bounds__(256) void bucket_kernel(const int* __restrict__ ei,
                                                     const float* __restrict__ ew,
                                                     int* __restrict__ cursor,
                                                     int* __restrict__ col_s,
                                                     float* __restrict__ ew_s) {
  int e = blockIdx.x * 256 + threadIdx.x;
  if (e >= N_EDGES) return;
  int r = ei[e];
  r = (r < 0) ? 0 : (r >= N_NODES ? N_NODES - 1 : r);
  int c = ei[N_EDGES + e];
  c = (c < 0) ? 0 : (c >= N_NODES ? N_NODES - 1 : c);
  int pos = atomicAdd(&cursor[r], 1);
  col_s[pos] = c;
  ew_s[pos] = ew[e];
}

// ---------------------------------------------------------------------------
// Aggregation R3: one wave per row. Lane l: edge-slot es=l>>5, channel group
// cg=l&31 (4 channels as uint2, 8B). 2 edges wave-parallel, unroll 4 (8 edges
// per iter) -> 4 independent 8B gathers in flight per lane. One shfl_xor(32)
// reduce at the end. agg[r,:] = invc[r] * sum_e ew_e * hlin[col_e,:]
// ---------------------------------------------------------------------------
__global__ __launch_bounds__(256) void agg_kernel(const unsigned short* __restrict__ hlin,
                                                  const int* __restrict__ rowptr,
                                                  const int* __restrict__ cnt,
                                                  const int* __restrict__ col_s,
                                                  const float* __restrict__ ew_s,
                                                  const float* __restrict__ invc,
                                                  unsigned short* __restrict__ agg) {
  const int r = blockIdx.x * 4 + (threadIdx.x >> 6);
  const int lane = threadIdx.x & 63;
  const int es = lane >> 5;          // 0/1: which of 2 parallel edges
  const int cg = lane & 31;          // channel group: channels cg*4..cg*4+3
  const int start = rowptr[r];
  const int num = cnt[r];
  const uint2* __restrict__ H = (const uint2*)hlin;   // row stride 32 uint2

  float a0 = 0.f, a1 = 0.f, a2 = 0.f, a3 = 0.f;
  for (int e = 0; e < num; e += 8) {
#pragma unroll
    for (int j = 0; j < 4; ++j) {
      int idx = e + j * 2 + es;
      int ok = idx < num;
      int idxc = ok ? idx : (num - 1);
      int c = col_s[start + idxc];
      float w = ok ? ew_s[start + idxc] : 0.0f;
      uint2 p = H[(size_t)c * 32 + cg];
      a0 += w * bflo(p.x);
      a1 += w * bfhi(p.x);
      a2 += w * bflo(p.y);
      a3 += w * bfhi(p.y);
    }
  }
  a0 += __shfl_xor(a0, 32);
  a1 += __shfl_xor(a1, 32);
  a2 += __shfl_xor(a2, 32);
  a3 += __shfl_xor(a3, 32);
  if (es == 0) {
    float s = invc[r];
    uint2 o;
    o.x = (unsigned)f2bf(a0 * s) | ((unsigned)f2bf(a1 * s) << 16);
    o.y = (unsigned)f2bf(a2 * s) | ((unsigned)f2bf(a3 * s) << 16);
    ((uint2*)agg)[(size_t)r * 32 + cg] = o;
  }
}

// ---------------------------------------------------------------------------
// bf16 MFMA GEMM, 64x64 tile (occupancy-optimized): out = [A0|A1] @ W + bias.
// Grid: (ceil(N/64) * 2) blocks; mt=bid>>1, nt=bid&1. Block 256 thr = 4 waves
// in 2x2; wave = 32x32 = 2x2 MFMA 16x16x32 tiles. BK=64, LDS rows padded to 72.
// Wt is bf16 W^T (Wt[n*KTOT+k] = W[k,n]). Dropout mask is bit-packed:
// word = maskw[row*2 + nt], bit = col&63.
// ---------------------------------------------------------------------------
template <int KTOT, bool RELU, bool MASK, bool WF32, bool WBF>
__global__ __launch_bounds__(256) void mfma_gemm(
    const unsigned short* __restrict__ A0, const unsigned short* __restrict__ A1,
    const unsigned short* __restrict__ Wt, const float* __restrict__ bias,
    const unsigned long long* __restrict__ maskw,
    float* __restrict__ outf, unsigned short* __restrict__ outb) {
  constexpr int LDK = 72;           // 144 B rows: bank stride 4 -> <=2-way, free
  __shared__ unsigned short Als[64 * LDK];
  __shared__ unsigned short Bls[64 * LDK];
  const int tid = threadIdx.x;
  const int mt = blockIdx.x >> 1;
  const int nt = blockIdx.x & 1;
  const int m0 = mt * 64;
  const int lane = tid & 63;
  const int wid = tid >> 6;
  const int wm = (wid >> 1) * 32;
  const int wn = (wid & 1) * 32;
  const int lrow = tid >> 2;        // staging row 0..63
  const int lk = (tid & 3) * 16;    // staging k-chunk (16 elem = 32 B)

  int arow = m0 + lrow;
  if (arow >= N_NODES) arow = N_NODES - 1;

  f32x4 acc[2][2];
#pragma unroll
  for (int i = 0; i < 2; ++i)
#pragma unroll
    for (int j = 0; j < 2; ++j)
#pragma unroll
      for (int r = 0; r < 4; ++r) acc[i][j][r] = 0.0f;

  for (int kb = 0; kb < KTOT; kb += 64) {
    const unsigned short* Asrc = (kb < 128) ? A0 : A1;
    const unsigned short* ap = Asrc + (size_t)arow * 128 + (kb & 127) + lk;
    const unsigned short* bp = Wt + (size_t)(nt * 64 + lrow) * KTOT + kb + lk;
    unsigned short* al = &Als[lrow * LDK + lk];
    unsigned short* bl = &Bls[lrow * LDK + lk];
    *(uint4*)(al + 0) = *(const uint4*)(ap + 0);
    *(uint4*)(al + 8) = *(const uint4*)(ap + 8);
    *(uint4*)(bl + 0) = *(const uint4*)(bp + 0);
    *(uint4*)(bl + 8) = *(const uint4*)(bp + 8);
    __syncthreads();
#pragma unroll
    for (int ks = 0; ks < 64; ks += 32) {
      bf16x8 af[2], bfr[2];
#pragma unroll
      for (int t = 0; t < 2; ++t) {
        af[t]  = *(const bf16x8*)&Als[(wm + t * 16 + (lane & 15)) * LDK + ks + (lane >> 4) * 8];
        bfr[t] = *(const bf16x8*)&Bls[(wn + t * 16 + (lane & 15)) * LDK + ks + (lane >> 4) * 8];
      }
#pragma unroll
      for (int i = 0; i < 2; ++i)
#pragma unroll
        for (int j = 0; j < 2; ++j)
          acc[i][j] = __builtin_amdgcn_mfma_f32_16x16x32_bf16(af[i], bfr[j], acc[i][j], 0, 0, 0);
    }
    __syncthreads();
  }

  // epilogue: C/D map col=lane&15, row=(lane>>4)*4+reg  [m89/m91]
  const int lm = lane >> 4;
  const int ln = lane & 15;
  float bcol[2];
#pragma unroll
  for (int j = 0; j < 2; ++j) bcol[j] = bias[nt * 64 + wn + j * 16 + ln];

#pragma unroll
  for (int i = 0; i < 2; ++i) {
    const int rbase = m0 + wm + i * 16 + lm * 4;
#pragma unroll
    for (int r = 0; r < 4; ++r) {
      const int row = rbase + r;
      if (row >= N_NODES) continue;
      unsigned long long mw = 0;
      if (MASK) mw = maskw[(size_t)row * 2 + nt];
#pragma unroll
      for (int j = 0; j < 2; ++j) {
        const int col = nt * 64 + wn + j * 16 + ln;
        float v = acc[i][j][r] + bcol[j];
        if (RELU) v = fmaxf(v, 0.0f);
        if (MASK) v = ((mw >> (wn + j * 16 + ln)) & 1ull) ? 2.0f * v : 0.0f;
        if (WF32) outf[(size_t)row * DGN + col] = v;
        if (WBF)  outb[(size_t)row * DGN + col] = f2bf(v);
      }
    }
  }
}

// ---------------------------------------------------------------------------
// MLP head 2: y[N,10] = t[N,128](bf16) @ W2[128,10] + b2. Row/thread, W2 in LDS.
// ---------------------------------------------------------------------------
__global__ __launch_bounds__(256) void mlp2_kernel(const unsigned short* __restrict__ t,
                                                   const float* __restrict__ W2,
                                                   const float* __restrict__ b2,
                                                   float* __restrict__ y) {
  __shared__ float Ws[128 * DOUT];
  __shared__ float bs[DOUT];
  for (int i = threadIdx.x; i < 128 * DOUT; i += 256) Ws[i] = W2[i];
  if (threadIdx.x < DOUT) bs[threadIdx.x] = b2[threadIdx.x];
  __syncthreads();
  int row = blockIdx.x * 256 + threadIdx.x;
  if (row >= N_NODES) return;
  float acc[DOUT];
#pragma unroll
  for (int c = 0; c < DOUT; ++c) acc[c] = bs[c];
  const uint4* tp = (const uint4*)(t + (size_t)row * 128);
#pragma unroll 4
  for (int k8 = 0; k8 < 16; ++k8) {
    uint4 raw = tp[k8];
    unsigned w[4] = {raw.x, raw.y, raw.z, raw.w};
#pragma unroll
    for (int p = 0; p < 4; ++p) {
      float lo = bflo(w[p]);
      float hi = bfhi(w[p]);
      const float* wr = &Ws[(k8 * 8 + p * 2) * DOUT];
#pragma unroll
      for (int c = 0; c < DOUT; ++c)
        acc[c] += lo * wr[c] + hi * wr[DOUT + c];
    }
  }
  float* yp = y + (size_t)row * DOUT;
#pragma unroll
  for (int c = 0; c < DOUT; ++c) yp[c] = acc[c];
}

// ---------------------------------------------------------------------------
// Fused one-shot prep: x fp32->bf16 + 5 weight transposes (Wt[n*K+k]=bf16 W[k,n])
// ---------------------------------------------------------------------------
#define NCONV (NELEM / 4)           // 1,600,000 float4 groups
__global__ __launch_bounds__(256) void prep_kernel(
    const float* __restrict__ x, unsigned short* __restrict__ xb,
    const float* __restrict__ W0, const float* __restrict__ W1,
    const float* __restrict__ W2, const float* __restrict__ W3,
    const float* __restrict__ W4,
    unsigned short* __restrict__ T0, unsigned short* __restrict__ T1,
    unsigned short* __restrict__ T2, unsigned short* __restrict__ T3,
    unsigned short* __restrict__ T4) {
  int g = blockIdx.x * 256 + threadIdx.x;
  if (g < NCONV) {
    float4 v = ((const float4*)x)[g];
    ushort4 o;
    o.x = f2bf(v.x); o.y = f2bf(v.y); o.z = f2bf(v.z); o.w = f2bf(v.w);
    ((ushort4*)xb)[g] = o;
    return;
  }
  int j = g - NCONV;
  const float* src; unsigned short* dst; int K;
  if (j < 16384)                  { src = W0; dst = T0; K = 128; }
  else if ((j -= 16384) < 32768)  { src = W1; dst = T1; K = 256; }
  else if ((j -= 32768) < 16384)  { src = W2; dst = T2; K = 128; }
  else if ((j -= 16384) < 32768)  { src = W3; dst = T3; K = 256; }
  else if ((j -= 32768) < 16384)  { src = W4; dst = T4; K = 128; }
  else return;
  int n = j / K, k = j - n * K;
  dst[j] = f2bf(src[(size_t)k * 128 + n]);
}

// ---------------------------------------------------------------------------
extern "C" void kernel_launch(void* const* d_in, const int* in_sizes, int n_in,
                              void* d_out, int out_size, void* d_ws, size_t ws_size,
                              hipStream_t stream) {
  const float* x        = (const float*)d_in[0];
  const int*   ei       = (const int*)d_in[1];
  const float* ew       = (const float*)d_in[2];
  const float* W_lin_in = (const float*)d_in[3];
  const float* b_lin_in = (const float*)d_in[4];
  const float* W_agg_in = (const float*)d_in[5];
  const float* b_agg_in = (const float*)d_in[6];
  const float* W_lin_h  = (const float*)d_in[7];
  const float* b_lin_h  = (const float*)d_in[8];
  const float* W_agg_h  = (const float*)d_in[9];
  const float* b_agg_h  = (const float*)d_in[10];
  const float* W_mlp1   = (const float*)d_in[11];
  const float* b_mlp1   = (const float*)d_in[12];
  const float* W_mlp2   = (const float*)d_in[13];
  const float* b_mlp2   = (const float*)d_in[14];

  float* hout = (float*)d_out;
  float* yout = hout + (size_t)NELEM;

  char* p = (char*)d_ws;
  auto alloc = [&](size_t bytes) {
    char* q = p;
    p += (bytes + 255) & ~(size_t)255;
    return q;
  };
  int*   cnt    = (int*)alloc((size_t)N_NODES * 4);
  int*   rowptr = (int*)alloc((size_t)N_NODES * 4);
  int*   cursor = (int*)alloc((size_t)N_NODES * 4);
  float* invc   = (float*)alloc((size_t)N_NODES * 4);
  int*   bsum   = (int*)alloc(256 * 4);
  int*   boff   = (int*)alloc(256 * 4);
  int*   col_s  = (int*)alloc((size_t)N_EDGES * 4);
  float* ew_s   = (float*)alloc((size_t)N_EDGES * 4);
  unsigned short* xb   = (unsigned short*)alloc((size_t)NELEM * 2);
  unsigned short* f0b  = (unsigned short*)alloc((size_t)NELEM * 2);
  unsigned short* aggb = (unsigned short*)alloc((size_t)NELEM * 2);
  unsigned short* hA   = (unsigned short*)alloc((size_t)NELEM * 2);
  unsigned short* hB   = (unsigned short*)alloc((size_t)NELEM * 2);
  unsigned long long* mw0 = (unsigned long long*)alloc((size_t)NMASKW * 8);
  unsigned long long* mw1 = (unsigned long long*)alloc((size_t)NMASKW * 8);
  unsigned long long* mw2 = (unsigned long long*)alloc((size_t)NMASKW * 8);
  unsigned short* Tli = (unsigned short*)alloc(16384 * 2);
  unsigned short* Tai = (unsigned short*)alloc(32768 * 2);
  unsigned short* Tlh = (unsigned short*)alloc(16384 * 2);
  unsigned short* Tah = (unsigned short*)alloc(32768 * 2);
  unsigned short* Tm1 = (unsigned short*)alloc(16384 * 2);

  // dropout keys: jax.random.split(jax.random.key(42), 3), partitionable
  unsigned dk[3][2];
  for (unsigned i = 0; i < 3; ++i) tf2x32(0u, 42u, 0u, i, dk[i][0], dk[i][1]);

  const int EB = (N_EDGES + 255) / 256;
  const int NB = (N_NODES + 255) / 256;
  const int GB = ((N_NODES + 63) / 64) * 2;   // 782 M-tiles x 2 N-tiles = 1564
  const int AB = (N_NODES + 3) / 4;           // 12500 agg blocks (4 rows each)
  const int MB = (NELEM + 255) / 256;
  const int PB = (NCONV + 114688 + 255) / 256;

  // ---- CSR build ----
  hipMemsetAsync(cnt, 0, (size_t)N_NODES * 4, stream);
  count_kernel<<<EB, 256, 0, stream>>>(ei, cnt);
  scan_local<<<NB, 256, 0, stream>>>(cnt, rowptr, bsum);
  scan_bsum<<<1, 256, 0, stream>>>(bsum, boff, NB);
  scan_final<<<NB, 256, 0, stream>>>(rowptr, boff, cnt, cursor, invc);
  bucket_kernel<<<EB, 256, 0, stream>>>(ei, ew, cursor, col_s, ew_s);

  // ---- one-shot prep + all masks ----
  prep_kernel<<<PB, 256, 0, stream>>>(x, xb, W_lin_in, W_agg_in, W_lin_h,
                                      W_agg_h, W_mlp1, Tli, Tai, Tlh, Tah, Tm1);
  mask_gen3<<<MB, 256, 0, stream>>>(mw0, mw1, mw2, dk[0][0], dk[0][1],
                                    dk[1][0], dk[1][1], dk[2][0], dk[2][1]);

  // ---- layer 1 ----
  mfma_gemm<128, false, false, false, true><<<GB, 256, 0, stream>>>(
      xb, xb, Tli, b_lin_in, mw0, nullptr, f0b);
  agg_kernel<<<AB, 256, 0, stream>>>(f0b, rowptr, cnt, col_s, ew_s, invc, aggb);
  mfma_gemm<256, true, true, false, true><<<GB, 256, 0, stream>>>(
      aggb, xb, Tai, b_agg_in, mw0, nullptr, hA);

  // ---- layer 2 ----
  mfma_gemm<128, false, false, false, true><<<GB, 256, 0, stream>>>(
      hA, hA, Tlh, b_lin_h, mw0, nullptr, f0b);
  agg_kernel<<<AB, 256, 0, stream>>>(f0b, rowptr, cnt, col_s, ew_s, invc, aggb);
  mfma_gemm<256, true, true, false, true><<<GB, 256, 0, stream>>>(
      aggb, hA, Tah, b_agg_h, mw1, nullptr, hB);

  // ---- layer 3 (fp32 h straight to d_out + bf16 for mlp1) ----
  mfma_gemm<128, false, false, false, true><<<GB, 256, 0, stream>>>(
      hB, hB, Tlh, b_lin_h, mw0, nullptr, f0b);
  agg_kernel<<<AB, 256, 0, stream>>>(f0b, rowptr, cnt, col_s, ew_s, invc, aggb);
  mfma_gemm<256, true, true, true, true><<<GB, 256, 0, stream>>>(
      aggb, hB, Tah, b_agg_h, mw2, hout, hA);

  // ---- MLP head ----
  mfma_gemm<128, true, false, false, true><<<GB, 256, 0, stream>>>(
      hA, hA, Tm1, b_mlp1, mw0, nullptr, aggb);
  mlp2_kernel<<<NB, 256, 0, stream>>>(aggb, W_mlp2, b_mlp2, yout);
}